// Round 9
// baseline (191.063 us; speedup 1.0000x reference)
//
#include <hip/hip_runtime.h>
#include <hip/hip_bf16.h>

// ProjectionAggregating: B=4096, N=64, D=128
// out[b,d] = query_emb + final_refer / (1e-9 + ref_norm/query_norm*2.5)
// final_refer[b,d] = sum_n (h1@W2^T + b2)[b,n,d] * (refer_embs - start_embs*refer_r)[b,n,d]
// h1 = relu(query_r@W1a^T + refer_r@W1b^T + b1)   (W1a = W1[:, :128], W1b = W1[:, 128:])

typedef __attribute__((ext_vector_type(8))) short bf16x8;   // 8 bf16 = 4 VGPRs (MFMA A/B frag)
typedef __attribute__((ext_vector_type(4))) float f32x4;    // MFMA C/D frag

__device__ __forceinline__ unsigned short f2bf(float x) {      // RNE
    unsigned int u = __float_as_uint(x);
    u += 0x7FFFu + ((u >> 16) & 1u);
    return (unsigned short)(u >> 16);
}
// pack two f32 -> two bf16 (round-half-up; inputs finite randn)
__device__ __forceinline__ unsigned int pack2bf(float lo, float hi) {
    unsigned int ulo = __float_as_uint(lo) + 0x8000u;
    unsigned int uhi = __float_as_uint(hi) + 0x8000u;
    return (ulo >> 16) | (uhi & 0xFFFF0000u);
}

// ---- kernel 1: convert W1b (W1[:,128:256]) and W2 to bf16 into workspace ----
__global__ __launch_bounds__(256) void pa_prep(const float* __restrict__ W1,
                                               const float* __restrict__ W2,
                                               unsigned short* __restrict__ w1b,
                                               unsigned short* __restrict__ w2b) {
    int i = blockIdx.x * 256 + threadIdx.x;   // grid covers 32768
    if (i < 16384) {
        int d = i >> 7, k = i & 127;
        w1b[i] = f2bf(W1[d * 256 + 128 + k]);
    } else {
        int j = i - 16384;
        w2b[j] = f2bf(W2[j]);
    }
}

// ---- kernel 2: qv[b,d] = b1[d] + sum_k query_r[b,k] * W1[d,k]  (f32, exact) ----
__global__ __launch_bounds__(256) void pa_qv(const float* __restrict__ query_r,
                                             const float* __restrict__ W1,
                                             const float* __restrict__ b1,
                                             float* __restrict__ qv) {
    __shared__ float wa[128][129];
    __shared__ float sq[32][128];
    const int tid = threadIdx.x;
    const int b0 = blockIdx.x * 32;  // grid = 128 blocks

    for (int i = tid; i < 128 * 128; i += 256) {
        int d = i >> 7, k = i & 127;
        wa[d][k] = W1[d * 256 + k];
    }
    for (int i = tid; i < 32 * 128; i += 256) {
        sq[i >> 7][i & 127] = query_r[(size_t)b0 * 128 + i];
    }
    __syncthreads();

    const int d = tid & 127;
    const int rb = (tid >> 7) * 16;
    const float bb = b1[d];
    for (int j = 0; j < 16; ++j) {
        int r = rb + j;
        float a0 = 0.f, a1 = 0.f, a2 = 0.f, a3 = 0.f;
        #pragma unroll
        for (int k = 0; k < 128; k += 4) {
            a0 += sq[r][k + 0] * wa[d][k + 0];
            a1 += sq[r][k + 1] * wa[d][k + 1];
            a2 += sq[r][k + 2] * wa[d][k + 2];
            a3 += sq[r][k + 3] * wa[d][k + 3];
        }
        qv[(size_t)(b0 + r) * 128 + d] = bb + ((a0 + a1) + (a2 + a3));
    }
}

// ---- kernel 3: WAVE-INDEPENDENT pipeline, one block per b ----
// Wave wv owns neighbor rows wv*16..wv*16+15 and runs the full chain with NO
// block barriers until the final cross-wave reduce: A-frags straight from
// global (f32->bf16 pack), GEMM1 over all 8 col-tiles (W frags from L2-hot
// ws), h1 transpose through wave-PRIVATE LDS scratch (same-wave ds ordering,
// no barrier), GEMM2, register gather with per-lane e/s/r loads, shfl reduce.
// Waves drift apart -> continuous memory demand (fixes the measured ~20%
// memory duty cycle caused by barrier phase-locking in R1-R8).
__global__ __launch_bounds__(256, 3) void pa_main(
    const float* __restrict__ query_emb,
    const float* __restrict__ refer_embs,
    const float* __restrict__ refer_r,
    const float* __restrict__ start_embs,
    const float* __restrict__ qv,
    const unsigned short* __restrict__ w1b,
    const unsigned short* __restrict__ w2b,
    const float* __restrict__ b2,
    float* __restrict__ out) {
    __shared__ __align__(16) unsigned short sT[4][16 * 128]; // per-wave h1 scratch (4 KB each)
    __shared__ float sFin[4][128];
    __shared__ float sRed[4];

    const int b    = blockIdx.x;
    const int tid  = threadIdx.x;
    const int lane = tid & 63;
    const int wv   = tid >> 6;       // wave -> rows wv*16 .. wv*16+15
    const int hl   = lane & 15;
    const int qh   = lane >> 4;

    const size_t base = (size_t)b * 8192;

    // ---- per-lane small loads (L2/L3-hot) ----
    float qe = (tid < 128) ? query_emb[(size_t)b * 128 + tid] : 0.f;
    float qvr[8], b2r[8];
    #pragma unroll
    for (int ct = 0; ct < 8; ++ct) {
        qvr[ct] = qv[(size_t)b * 128 + ct * 16 + hl];
        b2r[ct] = b2[ct * 16 + hl];
    }

    // ---- A-frags: refer_r[row = wv*16+hl][k = ks*32+qh*8 ..+7], f32 -> bf16 ----
    bf16x8 af[4];
    {
        const float* gR = refer_r + base + (size_t)(wv * 16 + hl) * 128;
        float4 ra[8];
        #pragma unroll
        for (int ks = 0; ks < 4; ++ks) {
            ra[ks * 2]     = *(const float4*)(gR + ks * 32 + qh * 8);
            ra[ks * 2 + 1] = *(const float4*)(gR + ks * 32 + qh * 8 + 4);
        }
        #pragma unroll
        for (int ks = 0; ks < 4; ++ks) {
            union { unsigned int u[4]; bf16x8 v; } cv;
            cv.u[0] = pack2bf(ra[ks * 2].x,     ra[ks * 2].y);
            cv.u[1] = pack2bf(ra[ks * 2].z,     ra[ks * 2].w);
            cv.u[2] = pack2bf(ra[ks * 2 + 1].x, ra[ks * 2 + 1].y);
            cv.u[3] = pack2bf(ra[ks * 2 + 1].z, ra[ks * 2 + 1].w);
            af[ks] = cv.v;
        }
    }

    // ---- GEMM1: acc1[ct] = A(16 rows) x W1b(cols ct*16..+15), all 8 ct ----
    f32x4 acc1[8] = {};
    #pragma unroll
    for (int ct = 0; ct < 8; ++ct) {
        const unsigned short* wp = w1b + (size_t)(ct * 16 + hl) * 128 + qh * 8;
        bf16x8 w0 = *(const bf16x8*)(wp);
        bf16x8 w1 = *(const bf16x8*)(wp + 32);
        bf16x8 w2 = *(const bf16x8*)(wp + 64);
        bf16x8 w3 = *(const bf16x8*)(wp + 96);
        acc1[ct] = __builtin_amdgcn_mfma_f32_16x16x32_bf16(af[0], w0, acc1[ct], 0, 0, 0);
        acc1[ct] = __builtin_amdgcn_mfma_f32_16x16x32_bf16(af[1], w1, acc1[ct], 0, 0, 0);
        acc1[ct] = __builtin_amdgcn_mfma_f32_16x16x32_bf16(af[2], w2, acc1[ct], 0, 0, 0);
        acc1[ct] = __builtin_amdgcn_mfma_f32_16x16x32_bf16(af[3], w3, acc1[ct], 0, 0, 0);
    }

    // ---- epi1: h1 = relu(acc1 + qv[col]) -> wave-private scratch (bf16, XOR swz) ----
    // C/D: col = ct*16+hl, row_local = qh*4+j. No barrier: same-wave ds ordering.
    {
        unsigned short* sw = &sT[wv][0];
        #pragma unroll
        for (int ct = 0; ct < 8; ++ct) {
            const int col = ct * 16 + hl;
            #pragma unroll
            for (int j = 0; j < 4; ++j) {
                int row = qh * 4 + j;
                float h = acc1[ct][j] + qvr[ct];
                h = h > 0.0f ? h : 0.0f;
                int byte = row * 256 + ((col * 2) ^ ((row & 7) << 4));
                *(unsigned short*)((char*)sw + byte) = f2bf(h);
            }
        }
    }

    // ---- A2-frags: h1[row=hl][k=ks*32+qh*8..+7] from scratch (b128, swz) ----
    bf16x8 af2[4];
    {
        const unsigned short* sw = &sT[wv][0];
        const int rsw = (hl & 7) << 4;
        #pragma unroll
        for (int ks = 0; ks < 4; ++ks) {
            int byte = hl * 256 + ((ks * 64 + qh * 16) ^ rsw);
            af2[ks] = *(const bf16x8*)((const char*)sw + byte);
        }
    }

    // ---- GEMM2: acc2[ct] = h1(16 rows) x W2(cols ct*16..+15) ----
    f32x4 acc2[8] = {};
    #pragma unroll
    for (int ct = 0; ct < 8; ++ct) {
        const unsigned short* wp = w2b + (size_t)(ct * 16 + hl) * 128 + qh * 8;
        bf16x8 w0 = *(const bf16x8*)(wp);
        bf16x8 w1 = *(const bf16x8*)(wp + 32);
        bf16x8 w2 = *(const bf16x8*)(wp + 64);
        bf16x8 w3 = *(const bf16x8*)(wp + 96);
        acc2[ct] = __builtin_amdgcn_mfma_f32_16x16x32_bf16(af2[0], w0, acc2[ct], 0, 0, 0);
        acc2[ct] = __builtin_amdgcn_mfma_f32_16x16x32_bf16(af2[1], w1, acc2[ct], 0, 0, 0);
        acc2[ct] = __builtin_amdgcn_mfma_f32_16x16x32_bf16(af2[2], w2, acc2[ct], 0, 0, 0);
        acc2[ct] = __builtin_amdgcn_mfma_f32_16x16x32_bf16(af2[3], w3, acc2[ct], 0, 0, 0);
    }

    // ---- gather: p[ct] = sum_j (acc2[ct][j] + b2[col]) * (e - s*r) at C/D coords ----
    // Two 4-ct halves; each half's 48 loads issued as one burst.
    float p[8];
    const float* gE = refer_embs + base;
    const float* gS = start_embs + base;
    const float* gR = refer_r + base;
    #pragma unroll
    for (int hf = 0; hf < 2; ++hf) {
        float fe[16], fs[16], fr[16];
        #pragma unroll
        for (int c = 0; c < 4; ++c) {
            const int col = (hf * 4 + c) * 16 + hl;
            #pragma unroll
            for (int j = 0; j < 4; ++j) {
                int off = (wv * 16 + qh * 4 + j) * 128 + col;
                fe[c * 4 + j] = gE[off];
                fs[c * 4 + j] = gS[off];
                fr[c * 4 + j] = gR[off];
            }
        }
        #pragma unroll
        for (int c = 0; c < 4; ++c) {
            const int ct = hf * 4 + c;
            float pp = 0.f;
            #pragma unroll
            for (int j = 0; j < 4; ++j) {
                float bias = fe[c * 4 + j] - fs[c * 4 + j] * fr[c * 4 + j];
                pp += (acc2[ct][j] + b2r[ct]) * bias;
            }
            p[ct] = pp;
        }
    }
    // sum over the 4 qh groups sharing each col
    #pragma unroll
    for (int ct = 0; ct < 8; ++ct) {
        p[ct] += __shfl_xor(p[ct], 16);
        p[ct] += __shfl_xor(p[ct], 32);
    }
    if (qh == 0) {
        #pragma unroll
        for (int ct = 0; ct < 8; ++ct) sFin[wv][ct * 16 + hl] = p[ct];
    }
    __syncthreads();   // B1: all waves' sFin ready

    // ---- final: cross-wave sum, normalize, add query_emb ----
    float fv = 0.f;
    if (tid < 128) {
        fv = sFin[0][tid] + sFin[1][tid] + sFin[2][tid] + sFin[3][tid];
        float rn = fabsf(fv), qn = fabsf(qe);
        #pragma unroll
        for (int off = 1; off < 64; off <<= 1) {
            rn += __shfl_xor(rn, off);
            qn += __shfl_xor(qn, off);
        }
        if (lane == 0) { sRed[wv * 2] = rn; sRed[wv * 2 + 1] = qn; }
    }
    __syncthreads();   // B2: sRed ready
    if (tid < 128) {
        float RN = sRed[0] + sRed[2];
        float QN = sRed[1] + sRed[3];
        float scale = 1.0f / (1e-9f + (RN / QN) * 2.5f);
        out[(size_t)b * 128 + tid] = qe + fv * scale;
    }
}

extern "C" void kernel_launch(void* const* d_in, const int* in_sizes, int n_in,
                              void* d_out, int out_size, void* d_ws, size_t ws_size,
                              hipStream_t stream) {
    const float* query_emb  = (const float*)d_in[0];
    const float* refer_embs = (const float*)d_in[1];
    const float* query_r    = (const float*)d_in[2];
    const float* refer_r    = (const float*)d_in[3];
    const float* start_embs = (const float*)d_in[4];
    const float* W1         = (const float*)d_in[5];
    const float* b1         = (const float*)d_in[6];
    const float* W2         = (const float*)d_in[7];
    const float* b2         = (const float*)d_in[8];
    float* out = (float*)d_out;

    char* ws = (char*)d_ws;
    float* qv            = (float*)ws;                              // 4096*128*4 = 2 MB
    unsigned short* w1b  = (unsigned short*)(ws + 2 * 1024 * 1024); // 32 KB
    unsigned short* w2b  = w1b + 16384;                             // 32 KB

    pa_prep<<<128, 256, 0, stream>>>(W1, W2, w1b, w2b);
    pa_qv<<<128, 256, 0, stream>>>(query_r, W1, b1, qv);
    pa_main<<<4096, 256, 0, stream>>>(query_emb, refer_embs, refer_r, start_embs,
                                      qv, w1b, w2b, b2, out);
}

// Round 11
// 110.014 us; speedup vs baseline: 1.7367x; 1.7367x over previous
//
#include <hip/hip_runtime.h>
#include <hip/hip_bf16.h>

// ProjectionAggregating: B=4096, N=64, D=128
// out[b,d] = query_emb + final_refer / (1e-9 + ref_norm/query_norm*2.5)
// final_refer[b,d] = sum_n (h1@W2^T + b2)[b,n,d] * (refer_embs - start_embs*refer_r)[b,n,d]
// h1 = relu(query_r@W1a^T + refer_r@W1b^T + b1)   (W1a = W1[:, :128], W1b = W1[:, 128:])

typedef __attribute__((ext_vector_type(8))) short bf16x8;   // 8 bf16 = 4 VGPRs (MFMA A/B frag)
typedef __attribute__((ext_vector_type(4))) float f32x4;    // MFMA C/D frag

__device__ __forceinline__ unsigned short f2bf(float x) {      // RNE
    unsigned int u = __float_as_uint(x);
    u += 0x7FFFu + ((u >> 16) & 1u);
    return (unsigned short)(u >> 16);
}
__device__ __forceinline__ float bf2f(unsigned short h) {
    return __uint_as_float(((unsigned int)h) << 16);
}

// ---- kernel 1: convert W1b (W1[:,128:256]) and W2 to bf16 into workspace ----
__global__ __launch_bounds__(256) void pa_prep(const float* __restrict__ W1,
                                               const float* __restrict__ W2,
                                               unsigned short* __restrict__ w1b,
                                               unsigned short* __restrict__ w2b) {
    int i = blockIdx.x * 256 + threadIdx.x;   // grid covers 32768
    if (i < 16384) {
        int d = i >> 7, k = i & 127;
        w1b[i] = f2bf(W1[d * 256 + 128 + k]);
    } else {
        int j = i - 16384;
        w2b[j] = f2bf(W2[j]);
    }
}

// ---- kernel 2: qv[b,d] = b1[d] + sum_k query_r[b,k] * W1[d,k]  (f32, exact) ----
__global__ __launch_bounds__(256) void pa_qv(const float* __restrict__ query_r,
                                             const float* __restrict__ W1,
                                             const float* __restrict__ b1,
                                             float* __restrict__ qv) {
    __shared__ float wa[128][129];
    __shared__ float sq[32][128];
    const int tid = threadIdx.x;
    const int b0 = blockIdx.x * 32;  // grid = 128 blocks

    for (int i = tid; i < 128 * 128; i += 256) {
        int d = i >> 7, k = i & 127;
        wa[d][k] = W1[d * 256 + k];
    }
    for (int i = tid; i < 32 * 128; i += 256) {
        sq[i >> 7][i & 127] = query_r[(size_t)b0 * 128 + i];
    }
    __syncthreads();

    const int d = tid & 127;
    const int rb = (tid >> 7) * 16;
    const float bb = b1[d];
    for (int j = 0; j < 16; ++j) {
        int r = rb + j;
        float a0 = 0.f, a1 = 0.f, a2 = 0.f, a3 = 0.f;
        #pragma unroll
        for (int k = 0; k < 128; k += 4) {
            a0 += sq[r][k + 0] * wa[d][k + 0];
            a1 += sq[r][k + 1] * wa[d][k + 1];
            a2 += sq[r][k + 2] * wa[d][k + 2];
            a3 += sq[r][k + 3] * wa[d][k + 3];
        }
        qv[(size_t)(b0 + r) * 128 + d] = bb + ((a0 + a1) + (a2 + a3));
    }
}

// ---- kernel 3: ONE-CONVOY main kernel, one block per b ----
// All global traffic (r, e, s) is loaded in a single stage phase; bias = e-s*r
// is computed in f32 ONCE and parked in LDS as bf16. The tail of the kernel
// (GEMM2 -> gather -> norm) touches no global memory at all, so the per-block
// serial chain is {convoy -> GEMM1 -> B -> GEMM2+gather -> B -> out}: 3
// barriers (was 6), no attn LDS round-trip, no exposed tail latency trip.
// LDS = 16K sR + 16K sH + 16K sBias + ~0.5K = 48.9 KB -> 3 blocks/CU.
__global__ __launch_bounds__(256, 2) void pa_main(
    const float* __restrict__ query_emb,
    const float* __restrict__ refer_embs,
    const float* __restrict__ refer_r,
    const float* __restrict__ start_embs,
    const float* __restrict__ qv,
    const unsigned short* __restrict__ w1b,
    const unsigned short* __restrict__ w2b,
    const float* __restrict__ b2,
    float* __restrict__ out) {
    __shared__ __align__(16) unsigned short sR[64 * 128];    // refer_r bf16, XOR-swz (16 KB)
    __shared__ __align__(16) unsigned short sH[64 * 128];    // h1 bf16, XOR-swz (16 KB)
    __shared__ __align__(16) unsigned short sBias[64 * 128]; // bias bf16, XOR-swz (16 KB)
    __shared__ float sFin[128];
    __shared__ float sRed[4];

    const int b    = blockIdx.x;
    const int tid  = threadIdx.x;
    const int lane = tid & 63;
    const int wv   = tid >> 6;       // wave wv owns output cols [32*wv, 32*wv+32)
    const int hl   = lane & 15;
    const int qh   = lane >> 4;
    const int wcol = wv * 32;

    const size_t base = (size_t)b * 8192;
    const float4* rr4 = (const float4*)(refer_r + base);
    const float4* re4 = (const float4*)(refer_embs + base);
    const float4* se4 = (const float4*)(start_embs + base);

    // ---- stage: three PURE load loops (no interleaved consumption), then
    //      one pack loop. r is used twice (sR bf16 + f32 bias math). ----
    float4 rb[8], eb[8], sb[8];
    #pragma unroll
    for (int it = 0; it < 8; ++it) rb[it] = rr4[tid + it * 256];
    #pragma unroll
    for (int it = 0; it < 8; ++it) eb[it] = re4[tid + it * 256];
    #pragma unroll
    for (int it = 0; it < 8; ++it) sb[it] = se4[tid + it * 256];

    // small per-lane loads (retired by B1)
    float qv0  = qv[(size_t)b * 128 + wcol + hl];
    float qv1  = qv[(size_t)b * 128 + wcol + 16 + hl];
    float b2v0 = b2[wcol + hl];
    float b2v1 = b2[wcol + 16 + hl];
    float qe   = (tid < 128) ? query_emb[(size_t)b * 128 + tid] : 0.f;

    #pragma unroll
    for (int it = 0; it < 8; ++it) {
        int e0  = (tid + it * 256) * 4;
        int row = e0 >> 7;           // = it*8 + (tid>>5)
        int kc  = e0 & 127;          // = (tid&31)*4
        int byte = row * 256 + ((kc * 2) ^ ((row & 7) << 4));
        float4 r = rb[it], e = eb[it], s = sb[it];
        ushort4 rv;
        rv.x = f2bf(r.x); rv.y = f2bf(r.y); rv.z = f2bf(r.z); rv.w = f2bf(r.w);
        *(ushort4*)((char*)sR + byte) = rv;
        ushort4 bv;
        bv.x = f2bf(e.x - s.x * r.x);
        bv.y = f2bf(e.y - s.y * r.y);
        bv.z = f2bf(e.z - s.z * r.z);
        bv.w = f2bf(e.w - s.w * r.w);
        *(ushort4*)((char*)sBias + byte) = bv;
    }
    __syncthreads();   // B1: sR + sBias staged; all global reads of r/e/s done

    // ---- GEMM1: h1[row,col] = sum_k r[row,k] * W1b[col,k] ----
    bf16x8 bW[2][4];
    #pragma unroll
    for (int ct = 0; ct < 2; ++ct)
        #pragma unroll
        for (int ks = 0; ks < 4; ++ks)
            bW[ct][ks] = *(const bf16x8*)(w1b + (wcol + ct * 16 + hl) * 128 + ks * 32 + qh * 8);

    f32x4 acc1[4][2] = {};
    #pragma unroll
    for (int rt = 0; rt < 4; ++rt) {
        const int row = rt * 16 + hl;
        const int rsw = (row & 7) << 4;
        bf16x8 af[4];
        #pragma unroll
        for (int ks = 0; ks < 4; ++ks) {
            int byte = row * 256 + ((ks * 64 + qh * 16) ^ rsw);
            af[ks] = *(const bf16x8*)((const char*)sR + byte);
        }
        #pragma unroll
        for (int ct = 0; ct < 2; ++ct)
            #pragma unroll
            for (int ks = 0; ks < 4; ++ks)
                acc1[rt][ct] = __builtin_amdgcn_mfma_f32_16x16x32_bf16(af[ks], bW[ct][ks], acc1[rt][ct], 0, 0, 0);
    }

    // ---- epi1: h1 = relu(acc1 + qv[col]) -> sH ----
    // C/D: col = lane&15, row = (lane>>4)*4 + reg
    #pragma unroll
    for (int ct = 0; ct < 2; ++ct) {
        const int col = wcol + ct * 16 + hl;
        const float q = (ct == 0) ? qv0 : qv1;
        #pragma unroll
        for (int rt = 0; rt < 4; ++rt) {
            #pragma unroll
            for (int j = 0; j < 4; ++j) {
                int row = rt * 16 + qh * 4 + j;
                float h = acc1[rt][ct][j] + q;
                h = h > 0.0f ? h : 0.0f;
                int byte = row * 256 + ((col * 2) ^ ((row & 7) << 4));
                *(unsigned short*)((char*)sH + byte) = f2bf(h);
            }
        }
    }
    __syncthreads();   // B2: h1 ready

    // ---- GEMM2: attn[row,col] = sum_k h1[row,k] * W2[col,k] (stays in regs) ----
    bf16x8 bW2[2][4];
    #pragma unroll
    for (int ct = 0; ct < 2; ++ct)
        #pragma unroll
        for (int ks = 0; ks < 4; ++ks)
            bW2[ct][ks] = *(const bf16x8*)(w2b + (wcol + ct * 16 + hl) * 128 + ks * 32 + qh * 8);

    f32x4 acc2[4][2] = {};
    #pragma unroll
    for (int rt = 0; rt < 4; ++rt) {
        const int row = rt * 16 + hl;
        const int rsw = (row & 7) << 4;
        bf16x8 af[4];
        #pragma unroll
        for (int ks = 0; ks < 4; ++ks) {
            int byte = row * 256 + ((ks * 64 + qh * 16) ^ rsw);
            af[ks] = *(const bf16x8*)((const char*)sH + byte);
        }
        #pragma unroll
        for (int ct = 0; ct < 2; ++ct)
            #pragma unroll
            for (int ks = 0; ks < 4; ++ks)
                acc2[rt][ct] = __builtin_amdgcn_mfma_f32_16x16x32_bf16(af[ks], bW2[ct][ks], acc2[rt][ct], 0, 0, 0);
    }

    // ---- gather in registers: p[col] = sum_rows (acc2 + b2[col]) * bias[row,col]
    //      bias from LDS (bf16, 2B reads; 4 rows x 16 cols per instr, row-XOR
    //      spreads banks ~2-way = free). NO global traffic in this phase. ----
    float p0 = 0.f, p1 = 0.f;
    #pragma unroll
    for (int ct = 0; ct < 2; ++ct) {
        const int col = wcol + ct * 16 + hl;
        const float bb = (ct == 0) ? b2v0 : b2v1;
        float pp = 0.f;
        #pragma unroll
        for (int rt = 0; rt < 4; ++rt) {
            #pragma unroll
            for (int j = 0; j < 4; ++j) {
                int row  = rt * 16 + qh * 4 + j;
                int byte = row * 256 + ((col * 2) ^ ((row & 7) << 4));
                float bias = bf2f(*(const unsigned short*)((const char*)sBias + byte));
                pp += (acc2[rt][ct][j] + bb) * bias;
            }
        }
        if (ct == 0) p0 = pp; else p1 = pp;
    }
    // sum over the 4 qh groups sharing each col
    p0 += __shfl_xor(p0, 16); p0 += __shfl_xor(p0, 32);
    p1 += __shfl_xor(p1, 16); p1 += __shfl_xor(p1, 32);
    if (qh == 0) {
        sFin[wcol + hl]      = p0;
        sFin[wcol + 16 + hl] = p1;
    }
    __syncthreads();   // B3: sFin ready

    // ---- final: normalize + add query_emb ----
    float fv = 0.f;
    if (tid < 128) {
        fv = sFin[tid];
        float rn = fabsf(fv), qn = fabsf(qe);
        #pragma unroll
        for (int off = 1; off < 64; off <<= 1) {
            rn += __shfl_xor(rn, off);
            qn += __shfl_xor(qn, off);
        }
        if (lane == 0) { sRed[wv * 2] = rn; sRed[wv * 2 + 1] = qn; }
    }
    __syncthreads();   // B4: sRed ready
    if (tid < 128) {
        float RN = sRed[0] + sRed[2];
        float QN = sRed[1] + sRed[3];
        float scale = 1.0f / (1e-9f + (RN / QN) * 2.5f);
        out[(size_t)b * 128 + tid] = qe + fv * scale;
    }
}

extern "C" void kernel_launch(void* const* d_in, const int* in_sizes, int n_in,
                              void* d_out, int out_size, void* d_ws, size_t ws_size,
                              hipStream_t stream) {
    const float* query_emb  = (const float*)d_in[0];
    const float* refer_embs = (const float*)d_in[1];
    const float* query_r    = (const float*)d_in[2];
    const float* refer_r    = (const float*)d_in[3];
    const float* start_embs = (const float*)d_in[4];
    const float* W1         = (const float*)d_in[5];
    const float* b1         = (const float*)d_in[6];
    const float* W2         = (const float*)d_in[7];
    const float* b2         = (const float*)d_in[8];
    float* out = (float*)d_out;

    char* ws = (char*)d_ws;
    float* qv            = (float*)ws;                              // 4096*128*4 = 2 MB
    unsigned short* w1b  = (unsigned short*)(ws + 2 * 1024 * 1024); // 32 KB
    unsigned short* w2b  = w1b + 16384;                             // 32 KB

    pa_prep<<<128, 256, 0, stream>>>(W1, W2, w1b, w2b);
    pa_qv<<<128, 256, 0, stream>>>(query_r, W1, b1, qv);
    pa_main<<<4096, 256, 0, stream>>>(query_emb, refer_embs, refer_r, start_embs,
                                      qv, w1b, w2b, b2, out);
}